// Round 7
// baseline (217.378 us; speedup 1.0000x reference)
//
#include <hip/hip_runtime.h>
#include <stdint.h>

#define N_PTS 100000
#define K_CL  256
#define F_DIM 256
#define XROW  264   // LDS row stride in shorts: 528B = 33*16B -> <=2-way bank aliasing

using bf16x8 = __attribute__((ext_vector_type(8))) short;
using f32x4  = __attribute__((ext_vector_type(4))) float;
typedef unsigned long long u64;

// RNE f32 -> bf16 bits (finite inputs only)
__device__ __forceinline__ unsigned short f32_to_bf16_rne(float f) {
    unsigned u = __float_as_uint(f);
    unsigned r = u + 0x7FFFu + ((u >> 16) & 1u);
    return (unsigned short)(r >> 16);
}

// ---------------- Kernel A: split c into bf16 hi/lo, csq, init best ------
__global__ void prep_kernel(const float* __restrict__ c,
                            unsigned short* __restrict__ ch,
                            unsigned short* __restrict__ cl,
                            float* __restrict__ csq,
                            u64* __restrict__ best) {
    const int k = blockIdx.x;      // one cluster per 64-thread block
    const int lane = threadIdx.x;
    float4 v = *(const float4*)(c + (size_t)k * F_DIM + lane * 4);

    float e[4] = {v.x, v.y, v.z, v.w};
    unsigned short hh[4], ll[4];
    #pragma unroll
    for (int i = 0; i < 4; ++i) {
        hh[i] = f32_to_bf16_rne(e[i]);
        float hf = __uint_as_float((unsigned)hh[i] << 16);
        ll[i] = f32_to_bf16_rne(e[i] - hf);
    }
    *(ushort4*)(ch + (size_t)k * F_DIM + lane * 4) = make_ushort4(hh[0], hh[1], hh[2], hh[3]);
    *(ushort4*)(cl + (size_t)k * F_DIM + lane * 4) = make_ushort4(ll[0], ll[1], ll[2], ll[3]);

    float s = v.x * v.x;
    s = fmaf(v.y, v.y, s);
    s = fmaf(v.z, v.z, s);
    s = fmaf(v.w, v.w, s);
    #pragma unroll
    for (int off = 32; off; off >>= 1) s += __shfl_down(s, off, 64);
    if (lane == 0) { csq[k] = s; best[k] = 0xFFFFFFFFFFFFFFFFULL; }
}

// ---------------- Kernel B: MFMA distance + argmin -----------------------
// Block = 512 threads = 8 waves, covers 64 points x 256 clusters; wave w:
// all 64 points x clusters [32w, 32w+32).
// Phase 1 (staging): whole x tile (64 pts x 256 feats) split fp32->bf16
// hi/lo into LDS; per wave-instr one full coalesced 1KB row; xsq reduced.
// ONE barrier. Phase 2 (compute): barrier-free 8x{c-frag loads, ds_read,
// 24 MFMA} — no vmcnt(0) drains anywhere in the hot path.
// mfma_f32_16x16x32_bf16 D layout: col=lane&15 (cluster), row=(lane>>4)*4+reg
// (point) [m89/m91]; A/B fragments are 8 contiguous K per lane.
__global__ __launch_bounds__(512, 4)
void cluster_argmin_kernel(const float* __restrict__ x,
                           const unsigned short* __restrict__ ch,
                           const unsigned short* __restrict__ cl,
                           const float* __restrict__ csq,
                           u64* __restrict__ best) {
    __shared__ unsigned short xh_lds[64][XROW];   // 33.8 KB
    __shared__ unsigned short xl_lds[64][XROW];   // 33.8 KB
    __shared__ float xsq_lds[64];

    const int tid  = threadIdx.x;
    const int lane = tid & 63;
    const int w    = __builtin_amdgcn_readfirstlane(tid >> 6);
    const int n0   = blockIdx.x * 64;
    const int r15  = lane & 15;
    const int kg   = lane >> 4;

    // ---- Phase 1: stage x tile (hi/lo) + xsq ----
    // wave w, step i handles tile row (w + 8i), cols lane*4 .. lane*4+3
    const int col = lane * 4;
    #pragma unroll
    for (int i = 0; i < 8; ++i) {
        const int row = w + i * 8;
        int gr = n0 + row; if (gr > N_PTS - 1) gr = N_PTS - 1;  // dup tail row
        float4 v = *(const float4*)(x + (size_t)gr * F_DIM + col);
        unsigned short h4[4], l4[4];
        float e[4] = {v.x, v.y, v.z, v.w};
        float s = 0.f;
        #pragma unroll
        for (int j = 0; j < 4; ++j) {
            h4[j] = f32_to_bf16_rne(e[j]);
            float hf = __uint_as_float((unsigned)h4[j] << 16);
            l4[j] = f32_to_bf16_rne(e[j] - hf);
            s = fmaf(e[j], e[j], s);
        }
        *(ushort4*)&xh_lds[row][col] = make_ushort4(h4[0], h4[1], h4[2], h4[3]);
        *(ushort4*)&xl_lds[row][col] = make_ushort4(l4[0], l4[1], l4[2], l4[3]);
        #pragma unroll
        for (int off = 32; off; off >>= 1) s += __shfl_xor(s, off, 64);
        if (lane == 0) xsq_lds[row] = s;
    }
    __syncthreads();   // the ONLY barrier

    // ---- Phase 2: barrier-free MFMA ----
    const int kb = w * 32;
    const unsigned short* cbh[2];
    const unsigned short* cbl[2];
    #pragma unroll
    for (int cg = 0; cg < 2; ++cg) {
        size_t off = (size_t)(kb + cg * 16 + r15) * F_DIM + kg * 8;
        cbh[cg] = ch + off;
        cbl[cg] = cl + off;
    }

    f32x4 acc[4][2];
    #pragma unroll
    for (int pg = 0; pg < 4; ++pg)
        #pragma unroll
        for (int cg = 0; cg < 2; ++cg)
            acc[pg][cg] = (f32x4){0.f, 0.f, 0.f, 0.f};

    #pragma unroll 2
    for (int it = 0; it < 8; ++it) {
        const int f0 = it * 32;
        bf16x8 bh[2], bl[2];
        #pragma unroll
        for (int cg = 0; cg < 2; ++cg) {
            bh[cg] = *(const bf16x8*)(cbh[cg] + f0);
            bl[cg] = *(const bf16x8*)(cbl[cg] + f0);
        }
        #pragma unroll
        for (int pg = 0; pg < 4; ++pg) {
            bf16x8 xh8 = *(const bf16x8*)&xh_lds[pg * 16 + r15][f0 + kg * 8];
            bf16x8 xl8 = *(const bf16x8*)&xl_lds[pg * 16 + r15][f0 + kg * 8];
            #pragma unroll
            for (int cg = 0; cg < 2; ++cg) {
                acc[pg][cg] = __builtin_amdgcn_mfma_f32_16x16x32_bf16(
                    xh8, bh[cg], acc[pg][cg], 0, 0, 0);
                acc[pg][cg] = __builtin_amdgcn_mfma_f32_16x16x32_bf16(
                    xh8, bl[cg], acc[pg][cg], 0, 0, 0);
                acc[pg][cg] = __builtin_amdgcn_mfma_f32_16x16x32_bf16(
                    xl8, bh[cg], acc[pg][cg], 0, 0, 0);
            }
        }
    }

    // ---- Epilogue: pack (sqrt-dist bits << 32 | n), per-cluster min ----
    u64 keep = 0xFFFFFFFFFFFFFFFFULL;
    #pragma unroll
    for (int cg = 0; cg < 2; ++cg) {
        const float cs = csq[kb + cg * 16 + r15];
        u64 m = 0xFFFFFFFFFFFFFFFFULL;
        #pragma unroll
        for (int pg = 0; pg < 4; ++pg) {
            #pragma unroll
            for (int r = 0; r < 4; ++r) {
                const int pl = pg * 16 + kg * 4 + r;   // point within tile
                const int n  = n0 + pl;
                float d2 = fmaf(-2.f, acc[pg][cg][r], xsq_lds[pl] + cs);
                d2 = fmaxf(d2, 0.f);
                float d = sqrtf(d2);
                u64 pk = ((u64)__float_as_uint(d) << 32) | (unsigned)n;
                if (n >= N_PTS) pk = 0xFFFFFFFFFFFFFFFFULL;
                m = pk < m ? pk : m;
            }
        }
        u64 o = __shfl_xor(m, 16, 64); m = o < m ? o : m;
        o = __shfl_xor(m, 32, 64);     m = o < m ? o : m;   // cluster kb+cg*16+r15
        if (kg == cg) keep = m;                              // lane<32 owns kb+lane
    }
    if (lane < 32) {
        u64 cur = best[kb + lane];                 // filter: stale is only ever >=
        if (keep < cur) atomicMin(&best[kb + lane], keep);
    }
}

// ---------------- Kernel C: gather winners ----------------
__global__ void gather_kernel(const float* __restrict__ x,
                              const u64* __restrict__ best,
                              float* __restrict__ out) {
    int k = blockIdx.x;
    unsigned int idx = (unsigned int)(best[k] & 0xFFFFFFFFULL);
    int t = threadIdx.x; // 64 threads, float4 each = 256 floats
    float4 v = *(const float4*)(x + (size_t)idx * F_DIM + t * 4);
    *(float4*)(out + (size_t)k * F_DIM + t * 4) = v;
}

extern "C" void kernel_launch(void* const* d_in, const int* in_sizes, int n_in,
                              void* d_out, int out_size, void* d_ws, size_t ws_size,
                              hipStream_t stream) {
    const float* x = (const float*)d_in[0];          // (1, N, F) f32
    const float* c = (const float*)d_in[1];          // (K, F)   f32
    float* out = (float*)d_out;                      // (1, K, F) f32

    u64* best  = (u64*)d_ws;                                         // 2 KB
    float* csq = (float*)((char*)d_ws + K_CL * sizeof(u64));         // 1 KB

    // c bf16 hi/lo live in d_out (256 KB, exact fit); final gather overwrites.
    unsigned short* ch = (unsigned short*)d_out;
    unsigned short* cl = ch + (size_t)K_CL * F_DIM;

    prep_kernel<<<K_CL, 64, 0, stream>>>(c, ch, cl, csq, best);

    int nblocks = (N_PTS + 63) / 64;   // 1563 blocks of 64 points
    cluster_argmin_kernel<<<nblocks, 512, 0, stream>>>(x, ch, cl, csq, best);

    gather_kernel<<<K_CL, 64, 0, stream>>>(x, best, out);
}

// Round 8
// 190.530 us; speedup vs baseline: 1.1409x; 1.1409x over previous
//
#include <hip/hip_runtime.h>
#include <hip/hip_bf16.h>
#include <stdint.h>

#define N_PTS 100000
#define K_CL  256
#define F_DIM 256

using bf16x8 = __attribute__((ext_vector_type(8))) short;
using f32x4  = __attribute__((ext_vector_type(4))) float;
typedef unsigned long long u64;

// 2x f32 -> packed 2x bf16 (RNE); compiler emits v_cvt_pk_bf16_f32
__device__ __forceinline__ unsigned pk2(float a, float b) {
    __hip_bfloat162 h = __float22bfloat162_rn(make_float2(a, b));
    unsigned u;
    __builtin_memcpy(&u, &h, 4);
    return u;
}

// ---------------- Kernel A: c -> fragment-contiguous bf16 hi/lo ----------
// Fragment layout: frag index fi = ((k/16)*8 + it)*64 + kg*16 + (k%16),
// 16 B per fragment (8 bf16 = feats it*32 + kg*8 .. +8 of cluster k).
// A wave-load of 64 consecutive fragments = one coalesced 1 KB read whose
// lane l gets cluster base+(l&15), feats kg=(l>>4) -> exact MFMA B operand.
__global__ void prep_kernel(const float* __restrict__ c,
                            unsigned short* __restrict__ chf,
                            unsigned short* __restrict__ clf,
                            float* __restrict__ csq,
                            u64* __restrict__ best) {
    const int k = blockIdx.x;      // one cluster per 64-thread block
    const int lane = threadIdx.x;
    float s = 0.f;
    if (lane < 32) {
        const int b = lane;                    // 8-feat block 0..31
        const float* src = c + (size_t)k * F_DIM + b * 8;
        float4 v0 = *(const float4*)(src);
        float4 v1 = *(const float4*)(src + 4);
        float e[8] = {v0.x, v0.y, v0.z, v0.w, v1.x, v1.y, v1.z, v1.w};
        unsigned h[4], l[4];
        #pragma unroll
        for (int j = 0; j < 4; ++j) {
            h[j] = pk2(e[2 * j], e[2 * j + 1]);
            float r0 = e[2 * j]     - __uint_as_float(h[j] << 16);
            float r1 = e[2 * j + 1] - __uint_as_float(h[j] & 0xFFFF0000u);
            l[j] = pk2(r0, r1);
            s = fmaf(e[2 * j], e[2 * j], s);
            s = fmaf(e[2 * j + 1], e[2 * j + 1], s);
        }
        const size_t fi = ((size_t)(k >> 4) * 8 + (b >> 2)) * 64
                        + (b & 3) * 16 + (k & 15);
        *(uint4*)(chf + fi * 8) = make_uint4(h[0], h[1], h[2], h[3]);
        *(uint4*)(clf + fi * 8) = make_uint4(l[0], l[1], l[2], l[3]);
    }
    #pragma unroll
    for (int off = 16; off; off >>= 1) s += __shfl_down(s, off, 64);
    if (lane == 0) { csq[k] = s; best[k] = 0xFFFFFFFFFFFFFFFFULL; }
}

// ---------------- Kernel B: MFMA distance + argmin -----------------------
// Block = 512 threads = 8 waves = 64 points x 256 clusters; wave w handles
// all 64 points x clusters [32w, 32w+32) (two 16-cluster groups g=2w,2w+1).
// Phase 1: stage x tile bf16 hi/lo into LDS — 8 independent coalesced row
// loads issued BEFORE conversion (all in flight), cvt_pk split, swizzled
// 16B-block layout p=(b+2*row)&31 (row stride 512 B) -> reads 2-way free.
// ONE barrier. Phase 2: barrier-free {1KB coalesced c-frag loads + ds_read
// + 24 MFMA}/it, setprio around MFMA. D layout: col=lane&15 (cluster),
// row=(lane>>4)*4+reg (point) [m89/m91].
__global__ __launch_bounds__(512, 4)
void cluster_argmin_kernel(const float* __restrict__ x,
                           const unsigned short* __restrict__ chf,
                           const unsigned short* __restrict__ clf,
                           const float* __restrict__ csq,
                           u64* __restrict__ best) {
    __shared__ unsigned short xh_lds[64 * 256];   // 32 KB, swizzled
    __shared__ unsigned short xl_lds[64 * 256];   // 32 KB, swizzled
    __shared__ float xsq_lds[64];

    const int tid  = threadIdx.x;
    const int lane = tid & 63;
    const int w    = __builtin_amdgcn_readfirstlane(tid >> 6);
    const int n0   = blockIdx.x * 64;
    const int r15  = lane & 15;
    const int kg   = lane >> 4;

    // ---- Phase 1: stage x tile ----
    // wave w, step i: tile row (w + 8i); lane covers cols lane*4..lane*4+3.
    float4 v[8];
    #pragma unroll
    for (int i = 0; i < 8; ++i) {
        int gr = n0 + w + i * 8;
        if (gr > N_PTS - 1) gr = N_PTS - 1;     // dup tail row; masked later
        v[i] = *(const float4*)(x + (size_t)gr * F_DIM + lane * 4);
    }
    #pragma unroll
    for (int i = 0; i < 8; ++i) {
        const int row = w + i * 8;
        float e[4] = {v[i].x, v[i].y, v[i].z, v[i].w};
        unsigned h01 = pk2(e[0], e[1]);
        unsigned h23 = pk2(e[2], e[3]);
        float r0 = e[0] - __uint_as_float(h01 << 16);
        float r1 = e[1] - __uint_as_float(h01 & 0xFFFF0000u);
        float r2 = e[2] - __uint_as_float(h23 << 16);
        float r3 = e[3] - __uint_as_float(h23 & 0xFFFF0000u);
        unsigned l01 = pk2(r0, r1);
        unsigned l23 = pk2(r2, r3);
        // swizzled store: logical 16B-block b=lane>>1, phys p=(b+2*row)&31
        const int p = ((lane >> 1) + 2 * row) & 31;
        const int so = row * 256 + p * 8 + (lane & 1) * 4;   // short offset
        *(uint2*)&xh_lds[so] = make_uint2(h01, h23);
        *(uint2*)&xl_lds[so] = make_uint2(l01, l23);
        float s = fmaf(e[0], e[0], 0.f);
        s = fmaf(e[1], e[1], s);
        s = fmaf(e[2], e[2], s);
        s = fmaf(e[3], e[3], s);
        #pragma unroll
        for (int off = 32; off; off >>= 1) s += __shfl_xor(s, off, 64);
        if (lane == 0) xsq_lds[row] = s;
    }
    __syncthreads();   // the ONLY barrier

    // ---- Phase 2: barrier-free MFMA ----
    const int kb = w * 32;
    // c fragment base pointers for this wave's two 16-cluster groups
    const unsigned short* fh0 = chf + ((size_t)(2 * w)     * 8) * 64 * 8 + lane * 8;
    const unsigned short* fh1 = chf + ((size_t)(2 * w + 1) * 8) * 64 * 8 + lane * 8;
    const unsigned short* fl0 = clf + ((size_t)(2 * w)     * 8) * 64 * 8 + lane * 8;
    const unsigned short* fl1 = clf + ((size_t)(2 * w + 1) * 8) * 64 * 8 + lane * 8;

    f32x4 acc[4][2];
    #pragma unroll
    for (int pg = 0; pg < 4; ++pg)
        #pragma unroll
        for (int cg = 0; cg < 2; ++cg)
            acc[pg][cg] = (f32x4){0.f, 0.f, 0.f, 0.f};

    #pragma unroll 2
    for (int it = 0; it < 8; ++it) {
        bf16x8 bh[2], bl[2];
        bh[0] = *(const bf16x8*)(fh0 + (size_t)it * 512);   // 64 frags * 8 shorts
        bh[1] = *(const bf16x8*)(fh1 + (size_t)it * 512);
        bl[0] = *(const bf16x8*)(fl0 + (size_t)it * 512);
        bl[1] = *(const bf16x8*)(fl1 + (size_t)it * 512);

        bf16x8 xh8[4], xl8[4];
        #pragma unroll
        for (int pg = 0; pg < 4; ++pg) {
            const int row = pg * 16 + r15;
            const int p = (4 * it + kg + 2 * row) & 31;     // swizzled block
            const int so = row * 256 + p * 8;
            xh8[pg] = *(const bf16x8*)&xh_lds[so];
            xl8[pg] = *(const bf16x8*)&xl_lds[so];
        }
        __builtin_amdgcn_s_setprio(1);
        #pragma unroll
        for (int pg = 0; pg < 4; ++pg) {
            #pragma unroll
            for (int cg = 0; cg < 2; ++cg) {
                acc[pg][cg] = __builtin_amdgcn_mfma_f32_16x16x32_bf16(
                    xh8[pg], bh[cg], acc[pg][cg], 0, 0, 0);
                acc[pg][cg] = __builtin_amdgcn_mfma_f32_16x16x32_bf16(
                    xh8[pg], bl[cg], acc[pg][cg], 0, 0, 0);
                acc[pg][cg] = __builtin_amdgcn_mfma_f32_16x16x32_bf16(
                    xl8[pg], bh[cg], acc[pg][cg], 0, 0, 0);
            }
        }
        __builtin_amdgcn_s_setprio(0);
    }

    // ---- Epilogue: pack (sqrt-dist bits << 32 | n), per-cluster min ----
    u64 keep = 0xFFFFFFFFFFFFFFFFULL;
    #pragma unroll
    for (int cg = 0; cg < 2; ++cg) {
        const float cs = csq[kb + cg * 16 + r15];
        u64 m = 0xFFFFFFFFFFFFFFFFULL;
        #pragma unroll
        for (int pg = 0; pg < 4; ++pg) {
            #pragma unroll
            for (int r = 0; r < 4; ++r) {
                const int pl = pg * 16 + kg * 4 + r;   // point within tile
                const int n  = n0 + pl;
                float d2 = fmaf(-2.f, acc[pg][cg][r], xsq_lds[pl] + cs);
                d2 = fmaxf(d2, 0.f);
                float d = sqrtf(d2);
                u64 pk = ((u64)__float_as_uint(d) << 32) | (unsigned)n;
                if (n >= N_PTS) pk = 0xFFFFFFFFFFFFFFFFULL;
                m = pk < m ? pk : m;
            }
        }
        u64 o = __shfl_xor(m, 16, 64); m = o < m ? o : m;
        o = __shfl_xor(m, 32, 64);     m = o < m ? o : m;   // cluster kb+cg*16+r15
        if (kg == cg) keep = m;                              // lane<32 owns kb+lane
    }
    if (lane < 32) {
        u64 cur = best[kb + lane];                 // filter: stale is only ever >=
        if (keep < cur) atomicMin(&best[kb + lane], keep);
    }
}

// ---------------- Kernel C: gather winners ----------------
__global__ void gather_kernel(const float* __restrict__ x,
                              const u64* __restrict__ best,
                              float* __restrict__ out) {
    int k = blockIdx.x;
    unsigned int idx = (unsigned int)(best[k] & 0xFFFFFFFFULL);
    int t = threadIdx.x; // 64 threads, float4 each = 256 floats
    float4 v = *(const float4*)(x + (size_t)idx * F_DIM + t * 4);
    *(float4*)(out + (size_t)k * F_DIM + t * 4) = v;
}

extern "C" void kernel_launch(void* const* d_in, const int* in_sizes, int n_in,
                              void* d_out, int out_size, void* d_ws, size_t ws_size,
                              hipStream_t stream) {
    const float* x = (const float*)d_in[0];          // (1, N, F) f32
    const float* c = (const float*)d_in[1];          // (K, F)   f32
    float* out = (float*)d_out;                      // (1, K, F) f32

    u64* best  = (u64*)d_ws;                                         // 2 KB
    float* csq = (float*)((char*)d_ws + K_CL * sizeof(u64));         // 1 KB

    // fragment-ordered c hi/lo live in d_out (128 KB + 128 KB = exact fit);
    // the final gather overwrites d_out.
    unsigned short* chf = (unsigned short*)d_out;
    unsigned short* clf = chf + (size_t)K_CL * F_DIM;

    prep_kernel<<<K_CL, 64, 0, stream>>>(c, chf, clf, csq, best);

    int nblocks = (N_PTS + 63) / 64;   // 1563 blocks of 64 points
    cluster_argmin_kernel<<<nblocks, 512, 0, stream>>>(x, chf, clf, csq, best);

    gather_kernel<<<K_CL, 64, 0, stream>>>(x, best, out);
}